// Round 5
// baseline (103.377 us; speedup 1.0000x reference)
//
#include <hip/hip_runtime.h>
#include <hip/hip_bf16.h>

#define N_NODES 4096
#define N_PER   128
#define D_DIM   64
#define CELLS   (32 * 128 * 128)     // 524288 cells; out = cells x 64 f32

#define STREAM_BLOCKS 1536
#define EDGE_BLOCKS   512
#define TOTAL_BLOCKS  (STREAM_BLOCKS + EDGE_BLOCKS)

// Fused: blocks [0,1024) init head=-1,cnt=0 (int4 stores);
//        blocks [1024,2048) compute p1/p2 projection (one wave per node).
//        block 1024 thread 0 also zeroes the worklist counter.
__global__ void init_proj(int4* __restrict__ head4, int4* __restrict__ cnt4,
                          int* __restrict__ wl_cnt,
                          const float* __restrict__ x,
                          const float* __restrict__ W,
                          const float* __restrict__ b,
                          float* __restrict__ p1,
                          float* __restrict__ p2) {
    if (blockIdx.x < 1024) {
        int i = blockIdx.x * 256 + threadIdx.x;          // 262144 int4 slots
        const int HC4 = CELLS / 4;                       // 131072
        if (i < HC4) head4[i] = make_int4(-1, -1, -1, -1);
        else         cnt4[i - HC4] = make_int4(0, 0, 0, 0);
    } else {
        if (blockIdx.x == 1024 && threadIdx.x == 0) *wl_cnt = 0;
        int n = (blockIdx.x - 1024) * 4 + (threadIdx.x >> 6);
        int d = threadIdx.x & 63;
        const float* xr = x + (size_t)n * D_DIM;
        const float* w  = W + (size_t)d * (2 * D_DIM);
        float a1 = b[d];
        float a2 = 0.0f;
#pragma unroll
        for (int k = 0; k < D_DIM; ++k) {
            float xv = xr[k];
            a1 += xv * w[k];
            a2 += xv * w[D_DIM + k];
        }
        p1[(size_t)n * D_DIM + d] = a1;
        p2[(size_t)n * D_DIM + d] = a2;
    }
}

// Edges: per-cell linked list via atomicExch; first edge into a cell appends
// the cell to the worklist. Tokens: per-cell int count (token contribution is
// cell-determined: p1[row] + p2[col]).
__global__ void link_count(const int* __restrict__ esrc,
                           const int* __restrict__ edst,
                           const int* __restrict__ tsrc,
                           const int* __restrict__ tdst,
                           int* __restrict__ head,
                           int* __restrict__ next,
                           int* __restrict__ cnt,
                           int* __restrict__ wl,
                           int* __restrict__ wl_cnt,
                           int E, int total) {
    int i = blockIdx.x * blockDim.x + threadIdx.x;
    if (i >= total) return;
    if (i < E) {
        int s = esrc[i], t = edst[i];
        int cell = ((s >> 7) << 14) | ((s & 127) << 7) | (t & 127);
        int prev = atomicExch(&head[cell], i);
        next[i] = prev;
        if (prev == -1) {                 // first edge in this cell
            int w = atomicAdd(wl_cnt, 1);
            wl[w] = cell;
        }
    } else {
        int j = i - E;
        int s = tsrc[j], t = tdst[j];
        int cell = ((s >> 7) << 14) | ((s & 127) << 7) | (t & 127);
        atomicAdd(&cnt[cell], 1);
    }
}

// Fused writer. 16 lanes (float4) per cell, 16 cells per 256-thread iteration.
// Blocks [0,STREAM_BLOCKS): pure stream over all cells, skip edge cells —
//   out[cell] = cnt[cell]*(p1[row]+p2[col]), branch-free inner math.
// Blocks [STREAM_BLOCKS,TOTAL): grid-stride the edge-cell worklist —
//   out[cell] = cnt*(p1+p2) + sum_{e in list} attr[e].
// Disjoint + complete: every cell written exactly once, no atomics.
__global__ void write_all(const int* __restrict__ head,
                          const int* __restrict__ next,
                          const int* __restrict__ cnt,
                          const float4* __restrict__ attr4,
                          const float4* __restrict__ p14,
                          const float4* __restrict__ p24,
                          const int* __restrict__ wl,
                          const int* __restrict__ wl_cnt,
                          float4* __restrict__ out4) {
    const int lane16 = threadIdx.x & 15;   // which float4 of the 64-d row
    const int grp    = threadIdx.x >> 4;   // 0..15 cells per iteration
    if (blockIdx.x < STREAM_BLOCKS) {
        for (int base = blockIdx.x * 16; base < CELLS; base += STREAM_BLOCKS * 16) {
            int cell = base + grp;
            if (head[cell] >= 0) continue;                    // edge cell: other half writes it
            int rownode = cell >> 7;                          // (g<<7)|r
            int colnode = ((cell >> 14) << 7) | (cell & 127); // (g<<7)|c
            float  f  = (float)cnt[cell];                     // 0 for empty
            float4 a  = p14[(size_t)rownode * 16 + lane16];
            float4 b2 = p24[(size_t)colnode * 16 + lane16];
            float4 v;
            v.x = f * (a.x + b2.x);
            v.y = f * (a.y + b2.y);
            v.z = f * (a.z + b2.z);
            v.w = f * (a.w + b2.w);
            out4[(size_t)cell * 16 + lane16] = v;
        }
    } else {
        const int n = *wl_cnt;                                // set by link_count
        for (int base = (blockIdx.x - STREAM_BLOCKS) * 16; base < n;
             base += EDGE_BLOCKS * 16) {
            int i = base + grp;
            if (i >= n) continue;
            int cell = wl[i];
            int rownode = cell >> 7;
            int colnode = ((cell >> 14) << 7) | (cell & 127);
            float  f  = (float)cnt[cell];
            float4 a  = p14[(size_t)rownode * 16 + lane16];
            float4 b2 = p24[(size_t)colnode * 16 + lane16];
            float4 v;
            v.x = f * (a.x + b2.x);
            v.y = f * (a.y + b2.y);
            v.z = f * (a.z + b2.z);
            v.w = f * (a.w + b2.w);
            for (int e = head[cell]; e >= 0; e = next[e]) {   // >=1 hop here
                float4 w = attr4[(size_t)e * 16 + lane16];
                v.x += w.x; v.y += w.y; v.z += w.z; v.w += w.w;
            }
            out4[(size_t)cell * 16 + lane16] = v;
        }
    }
}

extern "C" void kernel_launch(void* const* d_in, const int* in_sizes, int n_in,
                              void* d_out, int out_size, void* d_ws, size_t ws_size,
                              hipStream_t stream) {
    const float* x           = (const float*)d_in[0];
    const int*   edge_index  = (const int*)d_in[1];
    const float* edge_attr   = (const float*)d_in[2];
    // d_in[3] = batch (unused: indices are intra-graph with N_PER=128 stride)
    const int*   token_index = (const int*)d_in[4];
    const float* W           = (const float*)d_in[5];
    const float* b           = (const float*)d_in[6];

    const int E = in_sizes[1] / 2;   // 131072
    const int T = in_sizes[4] / 2;   // 131072

    float* out = (float*)d_out;
    // Workspace layout:
    float* p1     = (float*)d_ws;                          // 1 MB
    float* p2     = p1 + (size_t)N_NODES * D_DIM;          // 1 MB
    int*   head   = (int*)(p2 + (size_t)N_NODES * D_DIM);  // 2 MB
    int*   cnt    = head + CELLS;                          // 2 MB
    int*   next   = cnt + CELLS;                           // 0.5 MB
    int*   wl     = next + E;                              // 0.5 MB
    int*   wl_cnt = wl + E;                                // 4 B

    // 1. init head/cnt/wl_cnt + projection.
    init_proj<<<2048, 256, 0, stream>>>((int4*)head, (int4*)cnt, wl_cnt,
                                        x, W, b, p1, p2);

    // 2. edge linked-lists + worklist + token counts (4-B atomics to L2).
    int total = E + T;
    link_count<<<(total + 255) / 256, 256, 0, stream>>>(
        edge_index, edge_index + E, token_index, token_index + T,
        head, next, cnt, wl, wl_cnt, E, total);

    // 3. fused single-writer output: stream half + edge-worklist half.
    write_all<<<TOTAL_BLOCKS, 256, 0, stream>>>(head, next, cnt,
        (const float4*)edge_attr, (const float4*)p1, (const float4*)p2,
        wl, wl_cnt, (float4*)out);
}

// Round 6
// 100.459 us; speedup vs baseline: 1.0291x; 1.0291x over previous
//
#include <hip/hip_runtime.h>
#include <hip/hip_bf16.h>

#define N_NODES 4096
#define N_PER   128
#define D_DIM   64
#define CELLS   (32 * 128 * 128)     // 524288 cells; out = cells x 64 f32

// Fused: blocks [0,1024) init head=-1,cnt=0 (int4 stores);
//        blocks [1024,2048) compute p1/p2 projection (one wave per node).
//        block 1024 thread 0 also zeroes the wl2 counter.
__global__ void init_proj(int4* __restrict__ head4, int4* __restrict__ cnt4,
                          int* __restrict__ wl2_cnt,
                          const float* __restrict__ x,
                          const float* __restrict__ W,
                          const float* __restrict__ b,
                          float* __restrict__ p1,
                          float* __restrict__ p2) {
    if (blockIdx.x < 1024) {
        int i = blockIdx.x * 256 + threadIdx.x;          // 262144 int4 slots
        const int HC4 = CELLS / 4;                       // 131072
        if (i < HC4) head4[i] = make_int4(-1, -1, -1, -1);
        else         cnt4[i - HC4] = make_int4(0, 0, 0, 0);
    } else {
        if (blockIdx.x == 1024 && threadIdx.x == 0) *wl2_cnt = 0;
        int n = (blockIdx.x - 1024) * 4 + (threadIdx.x >> 6);
        int d = threadIdx.x & 63;
        const float* xr = x + (size_t)n * D_DIM;
        const float* w  = W + (size_t)d * (2 * D_DIM);
        float a1 = b[d];
        float a2 = 0.0f;
#pragma unroll
        for (int k = 0; k < D_DIM; ++k) {
            float xv = xr[k];
            a1 += xv * w[k];
            a2 += xv * w[D_DIM + k];
        }
        p1[(size_t)n * D_DIM + d] = a1;
        p2[(size_t)n * D_DIM + d] = a2;
    }
}

// Edges: per-cell linked list via atomicExch; an exchange returning a valid
// prev means this cell now has >=2 edges -> append cell to wl2 (duplicates ok,
// fix_multi is idempotent). Tokens: per-cell int count.
__global__ void link_count(const int* __restrict__ esrc,
                           const int* __restrict__ edst,
                           const int* __restrict__ tsrc,
                           const int* __restrict__ tdst,
                           int* __restrict__ head,
                           int* __restrict__ next,
                           int* __restrict__ cnt,
                           int* __restrict__ wl2,
                           int* __restrict__ wl2_cnt,
                           int E, int total) {
    int i = blockIdx.x * blockDim.x + threadIdx.x;
    if (i >= total) return;
    if (i < E) {
        int s = esrc[i], t = edst[i];
        int cell = ((s >> 7) << 14) | ((s & 127) << 7) | (t & 127);
        int prev = atomicExch(&head[cell], i);
        next[i] = prev;
        if (prev != -1) {                 // cell has >=2 edges now
            int w = atomicAdd(wl2_cnt, 1);
            wl2[w] = cell;
        }
    } else {
        int j = i - E;
        int s = tsrc[j], t = tdst[j];
        int cell = ((s >> 7) << 14) | ((s & 127) << 7) | (t & 127);
        atomicAdd(&cnt[cell], 1);
    }
}

// Stream pass over ALL cells: v = cnt*(p1+p2) + (head>=0 ? attr[head] : 0).
// No loop, unconditional full-wave stores (16 lanes x float4 per cell,
// 16 cells = 4KB contiguous per 256-thread block iteration).
// Cells with >=2 edges get a wrong value here; fix_multi overwrites them.
__global__ void stream_write(const int* __restrict__ head,
                             const int* __restrict__ cnt,
                             const float4* __restrict__ attr4,
                             const float4* __restrict__ p14,
                             const float4* __restrict__ p24,
                             float4* __restrict__ out4) {
    const int lane16 = threadIdx.x & 15;
    const int grp    = threadIdx.x >> 4;
#pragma unroll 4
    for (int base = blockIdx.x * 16; base < CELLS; base += 2048 * 16) {
        int cell = base + grp;
        int rownode = cell >> 7;                          // (g<<7)|r
        int colnode = ((cell >> 14) << 7) | (cell & 127); // (g<<7)|c
        float  f  = (float)cnt[cell];                     // 0 for empty
        float4 a  = p14[(size_t)rownode * 16 + lane16];
        float4 b2 = p24[(size_t)colnode * 16 + lane16];
        float4 v;
        v.x = f * (a.x + b2.x);
        v.y = f * (a.y + b2.y);
        v.z = f * (a.z + b2.z);
        v.w = f * (a.w + b2.w);
        int e = head[cell];
        if (e >= 0) {                                     // 22% of cells
            float4 w = attr4[(size_t)e * 16 + lane16];
            v.x += w.x; v.y += w.y; v.z += w.z; v.w += w.w;
        }
        out4[(size_t)cell * 16 + lane16] = v;
    }
}

// Idempotent full recompute for cells with >=2 edges (~2.6% of cells).
// Duplicate wl2 entries recompute the same value -> deterministic.
__global__ void fix_multi(const int* __restrict__ head,
                          const int* __restrict__ next,
                          const int* __restrict__ cnt,
                          const float4* __restrict__ attr4,
                          const float4* __restrict__ p14,
                          const float4* __restrict__ p24,
                          const int* __restrict__ wl2,
                          const int* __restrict__ wl2_cnt,
                          float4* __restrict__ out4) {
    const int lane16 = threadIdx.x & 15;
    const int grp    = threadIdx.x >> 4;
    const int n = *wl2_cnt;
    for (int base = blockIdx.x * 16; base < n; base += gridDim.x * 16) {
        int i = base + grp;
        if (i >= n) continue;
        int cell = wl2[i];
        int rownode = cell >> 7;
        int colnode = ((cell >> 14) << 7) | (cell & 127);
        float  f  = (float)cnt[cell];
        float4 a  = p14[(size_t)rownode * 16 + lane16];
        float4 b2 = p24[(size_t)colnode * 16 + lane16];
        float4 v;
        v.x = f * (a.x + b2.x);
        v.y = f * (a.y + b2.y);
        v.z = f * (a.z + b2.z);
        v.w = f * (a.w + b2.w);
        for (int e = head[cell]; e >= 0; e = next[e]) {   // full list, >=2
            float4 w = attr4[(size_t)e * 16 + lane16];
            v.x += w.x; v.y += w.y; v.z += w.z; v.w += w.w;
        }
        out4[(size_t)cell * 16 + lane16] = v;
    }
}

extern "C" void kernel_launch(void* const* d_in, const int* in_sizes, int n_in,
                              void* d_out, int out_size, void* d_ws, size_t ws_size,
                              hipStream_t stream) {
    const float* x           = (const float*)d_in[0];
    const int*   edge_index  = (const int*)d_in[1];
    const float* edge_attr   = (const float*)d_in[2];
    // d_in[3] = batch (unused: indices are intra-graph with N_PER=128 stride)
    const int*   token_index = (const int*)d_in[4];
    const float* W           = (const float*)d_in[5];
    const float* b           = (const float*)d_in[6];

    const int E = in_sizes[1] / 2;   // 131072
    const int T = in_sizes[4] / 2;   // 131072

    float* out = (float*)d_out;
    // Workspace layout:
    float* p1      = (float*)d_ws;                          // 1 MB
    float* p2      = p1 + (size_t)N_NODES * D_DIM;          // 1 MB
    int*   head    = (int*)(p2 + (size_t)N_NODES * D_DIM);  // 2 MB
    int*   cnt     = head + CELLS;                          // 2 MB
    int*   next    = cnt + CELLS;                           // 0.5 MB
    int*   wl2     = next + E;                              // 0.5 MB (worst case E)
    int*   wl2_cnt = wl2 + E;                               // 4 B

    // 1. init head/cnt/wl2_cnt + projection.
    init_proj<<<2048, 256, 0, stream>>>((int4*)head, (int4*)cnt, wl2_cnt,
                                        x, W, b, p1, p2);

    // 2. edge linked-lists + multi-edge worklist + token counts.
    int total = E + T;
    link_count<<<(total + 255) / 256, 256, 0, stream>>>(
        edge_index, edge_index + E, token_index, token_index + T,
        head, next, cnt, wl2, wl2_cnt, E, total);

    // 3. branch-light stream pass over all cells (first edge predicated in).
    stream_write<<<2048, 256, 0, stream>>>(head, cnt,
        (const float4*)edge_attr, (const float4*)p1, (const float4*)p2,
        (float4*)out);

    // 4. overwrite the ~2.6% multi-edge cells with full recompute.
    fix_multi<<<512, 256, 0, stream>>>(head, next, cnt,
        (const float4*)edge_attr, (const float4*)p1, (const float4*)p2,
        wl2, wl2_cnt, (float4*)out);
}

// Round 7
// 72.956 us; speedup vs baseline: 1.4170x; 1.3770x over previous
//
#include <hip/hip_runtime.h>
#include <hip/hip_bf16.h>

#define N_NODES 4096            // = ROWS (row key == global src node id)
#define N_PER   128
#define D_DIM   64
#define CELLS   (N_NODES * N_PER)   // 524288
#define CAP     128                 // max edges per src row (Poisson λ=32)

// Fused init + projection.
// blocks [0,516): zero cnt (131072 int4) + ecnt (1024 int4).
// blocks [516,1540): p1[n][d] = b[d] + x[n]·W[d][0:64]; p2[n][d] = x[n]·W[d][64:128].
__global__ void init_proj(int4* __restrict__ cnt4, int4* __restrict__ ecnt4,
                          const float* __restrict__ x,
                          const float* __restrict__ W,
                          const float* __restrict__ b,
                          float* __restrict__ p1,
                          float* __restrict__ p2) {
    if (blockIdx.x < 516) {
        int i = blockIdx.x * 256 + threadIdx.x;
        const int HC4 = CELLS / 4;               // 131072
        if (i < HC4)             cnt4[i] = make_int4(0, 0, 0, 0);
        else if (i < HC4 + 1024) ecnt4[i - HC4] = make_int4(0, 0, 0, 0);
    } else {
        int n = (blockIdx.x - 516) * 4 + (threadIdx.x >> 6);
        int d = threadIdx.x & 63;
        const float* xr = x + (size_t)n * D_DIM;
        const float* w  = W + (size_t)d * (2 * D_DIM);
        float a1 = b[d];
        float a2 = 0.0f;
#pragma unroll
        for (int k = 0; k < D_DIM; ++k) {
            float xv = xr[k];
            a1 += xv * w[k];
            a2 += xv * w[D_DIM + k];
        }
        p1[(size_t)n * D_DIM + d] = a1;
        p2[(size_t)n * D_DIM + d] = a2;
    }
}

// Edges: bucket by src row s into eslots[s*CAP + slot] = (c<<17)|e  (e<2^17, c<128).
// Tokens: per-cell count (token value is cell-determined: p1[row]+p2[col]).
__global__ void link(const int* __restrict__ esrc,
                     const int* __restrict__ edst,
                     const int* __restrict__ tsrc,
                     const int* __restrict__ tdst,
                     int* __restrict__ ecnt,
                     int* __restrict__ eslots,
                     int* __restrict__ cnt,
                     int E, int total) {
    int i = blockIdx.x * blockDim.x + threadIdx.x;
    if (i >= total) return;
    if (i < E) {
        int s = esrc[i];                       // row key 0..4095
        int c = edst[i] & 127;
        int slot = atomicAdd(&ecnt[s], 1);
        if (slot < CAP) eslots[(size_t)s * CAP + slot] = (c << 17) | i;
    } else {
        int j = i - E;
        int s = tsrc[j];
        int cell = (s << 7) | (tdst[j] & 127);
        atomicAdd(&cnt[cell], 1);
    }
}

// One block per row k=(g<<7)|r. LDS tile = out[g,r,:,:] (128 c-rows x 64 d).
// A: lds[c][d] = cnt[k*128+c] * (p1[k][d] + p2[(g<<7)|c][d])   (float4, full-wave)
// B: wave w accumulates edges with c in [32w,32w+32) -> disjoint LDS, no atomics.
// C: barrier, contiguous 32KB store.
__global__ void __launch_bounds__(256, 4)
row_combine(const int* __restrict__ ecnt,
            const int* __restrict__ eslots,
            const int* __restrict__ cnt,
            const float* __restrict__ attr,
            const float4* __restrict__ p14,
            const float4* __restrict__ p24,
            float4* __restrict__ out4) {
    __shared__ float lds[N_PER * D_DIM];       // 32 KB
    const int k      = blockIdx.x;             // row key
    const int gbase  = k & ~127;               // (g<<7)
    const int wave   = threadIdx.x >> 6;       // 0..3
    const int grp    = (threadIdx.x >> 4) & 3; // 0..3 within wave
    const int lane16 = threadIdx.x & 15;
    const int d      = threadIdx.x & 63;

    // Phase A: token term. Wave w fills c in [32w, 32w+32), 4 c per iteration.
    float4 p1v = p14[(size_t)k * 16 + lane16];             // broadcast per group
#pragma unroll
    for (int it = 0; it < 8; ++it) {
        int c = wave * 32 + it * 4 + grp;
        float f = (float)cnt[(k << 7) + c];                // uniform per group
        float4 p2v = p24[(size_t)(gbase | c) * 16 + lane16];
        float4 v;
        v.x = f * (p1v.x + p2v.x);
        v.y = f * (p1v.y + p2v.y);
        v.z = f * (p1v.z + p2v.z);
        v.w = f * (p1v.w + p2v.w);
        *(float4*)&lds[c * D_DIM + lane16 * 4] = v;
    }

    // Phase B: edge accumulation. Wave w owns c>>5 == w; same c-range it wrote
    // in A, so no barrier needed between A and B.
    int nE = ecnt[k];
    if (nE > CAP) nE = CAP;
    const int* slots = eslots + (size_t)k * CAP;
    for (int i = 0; i < nE; ++i) {
        int p = slots[i];                                  // uniform (scalar load)
        int c = p >> 17;
        if ((c >> 5) == wave) {                            // wave-uniform branch
            int e = p & 0x1FFFF;
            float av = attr[(size_t)e * D_DIM + d];        // 256B coalesced gather
            lds[c * D_DIM + d] += av;
        }
    }

    __syncthreads();

    // Phase C: contiguous 32KB store. 2048 float4 by 256 threads x 8.
    float4* dst = out4 + (size_t)k * (N_PER * D_DIM / 4);
#pragma unroll
    for (int it = 0; it < 8; ++it) {
        int idx = it * 256 + threadIdx.x;
        dst[idx] = *(float4*)&lds[idx * 4];
    }
}

extern "C" void kernel_launch(void* const* d_in, const int* in_sizes, int n_in,
                              void* d_out, int out_size, void* d_ws, size_t ws_size,
                              hipStream_t stream) {
    const float* x           = (const float*)d_in[0];
    const int*   edge_index  = (const int*)d_in[1];
    const float* edge_attr   = (const float*)d_in[2];
    // d_in[3] = batch (unused: indices are intra-graph with N_PER=128 stride)
    const int*   token_index = (const int*)d_in[4];
    const float* W           = (const float*)d_in[5];
    const float* b           = (const float*)d_in[6];

    const int E = in_sizes[1] / 2;   // 131072
    const int T = in_sizes[4] / 2;   // 131072

    // Workspace layout (~6 MB):
    float* p1     = (float*)d_ws;                          // 1 MB
    float* p2     = p1 + (size_t)N_NODES * D_DIM;          // 1 MB
    int*   cnt    = (int*)(p2 + (size_t)N_NODES * D_DIM);  // 2 MB
    int*   ecnt   = cnt + CELLS;                           // 16 KB
    int*   eslots = ecnt + N_NODES;                        // 2 MB

    // 1. zero cnt/ecnt + projection.
    init_proj<<<1540, 256, 0, stream>>>((int4*)cnt, (int4*)ecnt, x, W, b, p1, p2);

    // 2. bucket edges by src row + token cell counts.
    int total = E + T;
    link<<<(total + 255) / 256, 256, 0, stream>>>(
        edge_index, edge_index + E, token_index, token_index + T,
        ecnt, eslots, cnt, E, total);

    // 3. one block per (g,r) row: LDS tile, single contiguous write.
    row_combine<<<N_NODES, 256, 0, stream>>>(
        ecnt, eslots, cnt, edge_attr,
        (const float4*)p1, (const float4*)p2, (float4*)d_out);
}

// Round 8
// 67.057 us; speedup vs baseline: 1.5416x; 1.0880x over previous
//
#include <hip/hip_runtime.h>
#include <hip/hip_bf16.h>

#define N_NODES 4096            // row key == global src node id (g<<7)|r
#define N_PER   128
#define D_DIM   64
#define CELLS   (N_NODES * N_PER)   // 524288
#define CAPQ    48              // per (row, c-quadrant) capacity; Poisson(8)

// Fused init + projection.
// blocks [0,528): zero cnt (131072 int4) + ecntq (4096 int4).
// blocks [528,1552): p1[n][d] = b[d] + x[n]·W[d][0:64]; p2[n][d] = x[n]·W[d][64:128].
__global__ void init_proj(int4* __restrict__ cnt4, int4* __restrict__ ecntq4,
                          const float* __restrict__ x,
                          const float* __restrict__ W,
                          const float* __restrict__ b,
                          float* __restrict__ p1,
                          float* __restrict__ p2) {
    if (blockIdx.x < 528) {
        int i = blockIdx.x * 256 + threadIdx.x;
        if (i < 131072)            cnt4[i] = make_int4(0, 0, 0, 0);
        else if (i < 131072 + 4096) ecntq4[i - 131072] = make_int4(0, 0, 0, 0);
    } else {
        int n = (blockIdx.x - 528) * 4 + (threadIdx.x >> 6);
        int d = threadIdx.x & 63;
        const float* xr = x + (size_t)n * D_DIM;
        const float* w  = W + (size_t)d * (2 * D_DIM);
        float a1 = b[d];
        float a2 = 0.0f;
#pragma unroll
        for (int k = 0; k < D_DIM; ++k) {
            float xv = xr[k];
            a1 += xv * w[k];
            a2 += xv * w[D_DIM + k];
        }
        p1[(size_t)n * D_DIM + d] = a1;
        p2[(size_t)n * D_DIM + d] = a2;
    }
}

// Edges: bucket by (src row, dst quadrant) -> eslots[(s*4+q)*CAPQ + slot] =
// (c<<17)|e  (e < 2^17, c < 128). Tokens: per-cell count.
__global__ void link(const int* __restrict__ esrc,
                     const int* __restrict__ edst,
                     const int* __restrict__ tsrc,
                     const int* __restrict__ tdst,
                     int* __restrict__ ecntq,
                     int* __restrict__ eslots,
                     int* __restrict__ cnt,
                     int E, int total) {
    int i = blockIdx.x * blockDim.x + threadIdx.x;
    if (i >= total) return;
    if (i < E) {
        int s = esrc[i];                       // row key 0..4095
        int c = edst[i] & 127;
        int q = c >> 5;                        // wave that will consume it
        int slot = atomicAdd(&ecntq[s * 4 + q], 1);
        if (slot < CAPQ)
            eslots[(size_t)(s * 4 + q) * CAPQ + slot] = (c << 17) | i;
    } else {
        int j = i - E;
        int s = tsrc[j];
        int cell = (s << 7) | (tdst[j] & 127);
        atomicAdd(&cnt[cell], 1);
    }
}

// One block per row k. LDS tile = out[g,r,:,:] (128 c x 64 d = 32 KB).
// Wave w exclusively owns c in [32w, 32w+32) across ALL phases -> no barriers.
// A: lds[c][d] = cnt[(k<<7)+c] * (p1[k][d] + p2[(g<<7)|c][d])
// B: batched edge accumulate: 8 independent attr gathers in flight, then LDS adds.
// C: per-wave contiguous 8 KB store.
__global__ void __launch_bounds__(256, 4)
row_combine(const int* __restrict__ ecntq,
            const int* __restrict__ eslots,
            const int* __restrict__ cnt,
            const float* __restrict__ attr,
            const float4* __restrict__ p14,
            const float4* __restrict__ p24,
            float4* __restrict__ out4) {
    __shared__ float lds[N_PER * D_DIM];       // 32 KB
    const int k      = blockIdx.x;             // row key (g<<7)|r
    const int gbase  = k & ~127;               // g<<7
    const int wave   = threadIdx.x >> 6;       // 0..3 = c-quadrant owner
    const int grp    = (threadIdx.x >> 4) & 3;
    const int lane16 = threadIdx.x & 15;
    const int d      = threadIdx.x & 63;

    // Phase A: token term for this wave's 32 c-rows (4 per iteration).
    float4 p1v = p14[(size_t)k * 16 + lane16];
#pragma unroll
    for (int it = 0; it < 8; ++it) {
        int c = wave * 32 + it * 4 + grp;
        float f = (float)cnt[(k << 7) + c];
        float4 p2v = p24[(size_t)(gbase | c) * 16 + lane16];
        float4 v;
        v.x = f * (p1v.x + p2v.x);
        v.y = f * (p1v.y + p2v.y);
        v.z = f * (p1v.z + p2v.z);
        v.w = f * (p1v.w + p2v.w);
        *(float4*)&lds[c * D_DIM + lane16 * 4] = v;
    }

    // Phase B: this wave's private edge list, batches of 8 in-flight gathers.
    int nq = ecntq[k * 4 + wave];
    if (nq > CAPQ) nq = CAPQ;
    const int4* sl4 = (const int4*)(eslots + (size_t)(k * 4 + wave) * CAPQ);
    for (int i0 = 0; i0 < nq; i0 += 8) {
        int m = nq - i0;                       // >=1
        int4 w0 = sl4[i0 / 4];                 // reading past nq is safe (alloc'd)
        int4 w1 = sl4[i0 / 4 + 1];
        int pk[8] = {w0.x, w0.y, w0.z, w0.w, w1.x, w1.y, w1.z, w1.w};
        float av[8];
        int   cc[8];
#pragma unroll
        for (int j = 0; j < 8; ++j) {
            if (j < m) {
                cc[j] = pk[j] >> 17;
                av[j] = attr[(size_t)(pk[j] & 0x1FFFF) * D_DIM + d];
            }
        }
#pragma unroll
        for (int j = 0; j < 8; ++j)
            if (j < m) lds[cc[j] * D_DIM + d] += av[j];
    }

    // Phase C: store this wave's 32 rows (8 KB contiguous), no barrier needed.
    const int lane = threadIdx.x & 63;
    float4* dstw = out4 + (size_t)k * 2048 + wave * 512;
    const float* ldsw = lds + wave * 2048;
#pragma unroll
    for (int it = 0; it < 8; ++it) {
        int idx = it * 64 + lane;
        dstw[idx] = *(const float4*)&ldsw[idx * 4];
    }
}

extern "C" void kernel_launch(void* const* d_in, const int* in_sizes, int n_in,
                              void* d_out, int out_size, void* d_ws, size_t ws_size,
                              hipStream_t stream) {
    const float* x           = (const float*)d_in[0];
    const int*   edge_index  = (const int*)d_in[1];
    const float* edge_attr   = (const float*)d_in[2];
    // d_in[3] = batch (unused: indices are intra-graph with N_PER=128 stride)
    const int*   token_index = (const int*)d_in[4];
    const float* W           = (const float*)d_in[5];
    const float* b           = (const float*)d_in[6];

    const int E = in_sizes[1] / 2;   // 131072
    const int T = in_sizes[4] / 2;   // 131072

    // Workspace layout (~7.1 MB):
    float* p1     = (float*)d_ws;                          // 1 MB
    float* p2     = p1 + (size_t)N_NODES * D_DIM;          // 1 MB
    int*   cnt    = (int*)(p2 + (size_t)N_NODES * D_DIM);  // 2 MB
    int*   ecntq  = cnt + CELLS;                           // 64 KB
    int*   eslots = ecntq + N_NODES * 4;                   // 3 MB

    // 1. zero cnt/ecntq + projection.
    init_proj<<<1552, 256, 0, stream>>>((int4*)cnt, (int4*)ecntq, x, W, b, p1, p2);

    // 2. bucket edges by (row, quadrant) + token cell counts.
    int total = E + T;
    link<<<(total + 255) / 256, 256, 0, stream>>>(
        edge_index, edge_index + E, token_index, token_index + T,
        ecntq, eslots, cnt, E, total);

    // 3. one block per row: barrier-free LDS tile, batched gathers, streamed store.
    row_combine<<<N_NODES, 256, 0, stream>>>(
        ecntq, eslots, cnt, edge_attr,
        (const float4*)p1, (const float4*)p2, (float4*)d_out);
}